// Round 18
// baseline (395.832 us; speedup 1.0000x reference)
//
#include <hip/hip_runtime.h>
#include <hip/hip_bf16.h>

typedef _Float16 f16_t;
typedef unsigned int uint;
typedef __attribute__((ext_vector_type(8))) _Float16 f16x8;
typedef __attribute__((ext_vector_type(4))) _Float16 f16x4;
typedef __attribute__((ext_vector_type(4))) float f32x4;
typedef __attribute__((ext_vector_type(16))) float f32x16;

#define ROPE_C (13.287712379549449f / 64.0f)   // log2(10000)/64; invf(j)=exp2(-j*ROPE_C)

// ---------------- repack fp32 x [2048][4096] -> packed fp16 [16 pan][128 kb][128 r][32 c] ----------------
__global__ __launch_bounds__(256) void repack_x16(const float* __restrict__ src,
                                                  uint16_t* __restrict__ dh)
{
    const int p  = blockIdx.y;
    const int kb = blockIdx.x;
    const int tid = threadIdx.x;
    const int rr = tid >> 3;
    const int k4 = tid & 7;
    const int slot = k4 >> 1;
    const int so   = (k4 & 1) * 4;
    uint16_t* bh = dh + ((size_t)p * 128 + kb) * 4096;
    #pragma unroll
    for (int it = 0; it < 4; ++it) {
        const int r = it * 32 + rr;
        const float4 v = *reinterpret_cast<const float4*>(
            &src[((size_t)p * 128 + r) * 4096 + kb * 32 + k4 * 4]);
        float f[4] = {v.x, v.y, v.z, v.w};
        f16x4 h;
        #pragma unroll
        for (int e = 0; e < 4; ++e) h[e] = (f16_t)f[e];
        const int pos = r * 32 + ((slot ^ ((r >> 1) & 3)) << 3) + so;
        *reinterpret_cast<f16x4*>(&bh[pos]) = h;
    }
}

// ---------------- QKV GEMM: 128x192, fp16, BK=64, 2-buf, grid 512 (2 blocks/CU); 2-D XCD partition.
// A (x) staged via global_load_lds from packed fp16; B (wq|wk|wv) reg-staged from native fp32 + cvt.
__global__ __launch_bounds__(512) void gemm_qkv10(const uint16_t* __restrict__ xh,
                                                  const float* __restrict__ wq,
                                                  const float* __restrict__ wk,
                                                  const float* __restrict__ wv,
                                                  uint16_t* __restrict__ xq16,
                                                  uint16_t* __restrict__ xk16,
                                                  uint16_t* __restrict__ xv16)
{
    __shared__ char lds[2][40960];   // per buf: A 16K ([kk2][128r][32c]) | B 24K ([pan2][kk2][96r][32c])

    const int bid = blockIdx.x;
    const int xcd = bid & 7;
    const int i_  = bid >> 3;
    const int by = (xcd & 1) * 8 + (i_ & 7);
    const int bx = (xcd >> 1) * 8 + (i_ >> 3);
    const int tid = threadIdx.x;
    const int w = tid >> 6, lane = tid & 63;
    const int wm = w >> 2, wn = w & 3;
    const int fr = lane & 15, s4 = lane >> 4;

    // A staging: 16 chunks of 1 KB; wave w stages c = w + 8i, i=0..1
    const uint16_t* spA[2];
    int dofA[2];
    #pragma unroll
    for (int i = 0; i < 2; ++i) {
        const int c = w + 8 * i;
        spA[i] = xh + (size_t)by * 524288 + (c >> 3) * 4096 + (c & 7) * 512 + lane * 8;
        dofA[i] = c * 1024;
    }

    // B reg-staging: 3 units of 8 fp32 per thread
    const float* bsrc[3];
    int boff[3];
    #pragma unroll
    for (int i = 0; i < 3; ++i) {
        const int v = tid + 512 * i;
        const int row = v >> 3;            // 0..191
        const int s8  = v & 7;
        const int n = bx * 192 + row;
        const float* srow = (n < 4096) ? (wq + (size_t)n * 4096)
                          : (n < 5120) ? (wk + (size_t)(n - 4096) * 4096)
                                       : (wv + (size_t)(n - 5120) * 4096);
        bsrc[i] = srow + s8 * 8;
        const int pan = (row >= 96) ? 1 : 0;
        const int rb = row - pan * 96;
        boff[i] = 16384 + pan * 12288 + (s8 >> 2) * 6144 + rb * 64 + (((s8 & 3) ^ ((rb >> 1) & 3)) << 4);
    }

    f32x4 acc[4][3] = {};
    float4 br[3][2];

    // prologue: stage tile 0
    #pragma unroll
    for (int i = 0; i < 2; ++i)
        __builtin_amdgcn_global_load_lds(
            (const __attribute__((address_space(1))) void*)(spA[i]),
            (__attribute__((address_space(3))) void*)(&lds[0][0] + dofA[i]), 16, 0, 0);
    #pragma unroll
    for (int i = 0; i < 3; ++i) {
        br[i][0] = *reinterpret_cast<const float4*>(bsrc[i]);
        br[i][1] = *reinterpret_cast<const float4*>(bsrc[i] + 4);
    }
    asm volatile("s_waitcnt vmcnt(0)" ::: "memory");
    #pragma unroll
    for (int i = 0; i < 3; ++i) {
        f16x8 hx;
        hx[0] = (f16_t)br[i][0].x; hx[1] = (f16_t)br[i][0].y;
        hx[2] = (f16_t)br[i][0].z; hx[3] = (f16_t)br[i][0].w;
        hx[4] = (f16_t)br[i][1].x; hx[5] = (f16_t)br[i][1].y;
        hx[6] = (f16_t)br[i][1].z; hx[7] = (f16_t)br[i][1].w;
        *reinterpret_cast<f16x8*>(&lds[0][0] + boff[i]) = hx;
    }
    asm volatile("s_waitcnt lgkmcnt(0)" ::: "memory");
    __builtin_amdgcn_s_barrier();
    __builtin_amdgcn_sched_barrier(0);

    for (int t = 0; t < 64; ++t) {
        const char* b = &lds[t & 1][0];
        char* nb = &lds[(t + 1) & 1][0];
        const bool pre = (t + 1 < 64);
        if (pre) {
            #pragma unroll
            for (int i = 0; i < 3; ++i) {
                br[i][0] = *reinterpret_cast<const float4*>(bsrc[i] + (size_t)(t + 1) * 64);
                br[i][1] = *reinterpret_cast<const float4*>(bsrc[i] + (size_t)(t + 1) * 64 + 4);
            }
            #pragma unroll
            for (int i = 0; i < 2; ++i)
                __builtin_amdgcn_global_load_lds(
                    (const __attribute__((address_space(1))) void*)(spA[i] + (size_t)(t + 1) * 8192),
                    (__attribute__((address_space(3))) void*)(nb + dofA[i]), 16, 0, 0);
        }
        #pragma unroll
        for (int kk = 0; kk < 2; ++kk) {
            f16x8 fb[3];
            #pragma unroll
            for (int j = 0; j < 3; ++j) {
                const int cbp = wn * 48 + j * 16 + fr;
                const int pan = (cbp >= 96) ? 1 : 0;
                const int rb = cbp - pan * 96;
                fb[j] = *reinterpret_cast<const f16x8*>(
                    b + 16384 + pan * 12288 + kk * 6144 + rb * 64 + ((s4 ^ ((rb >> 1) & 3)) << 4));
            }
            #pragma unroll
            for (int ri = 0; ri < 4; ++ri) {
                const int rloc = wm * 64 + ri * 16 + fr;
                f16x8 fh = *reinterpret_cast<const f16x8*>(
                    b + kk * 8192 + rloc * 64 + ((s4 ^ ((rloc >> 1) & 3)) << 4));
                __builtin_amdgcn_s_setprio(1);
                #pragma unroll
                for (int j = 0; j < 3; ++j)
                    acc[ri][j] = __builtin_amdgcn_mfma_f32_16x16x32_f16(fh, fb[j], acc[ri][j], 0, 0, 0);
                __builtin_amdgcn_s_setprio(0);
            }
        }
        asm volatile("s_waitcnt vmcnt(0)" ::: "memory");
        if (pre) {
            #pragma unroll
            for (int i = 0; i < 3; ++i) {
                f16x8 hx;
                hx[0] = (f16_t)br[i][0].x; hx[1] = (f16_t)br[i][0].y;
                hx[2] = (f16_t)br[i][0].z; hx[3] = (f16_t)br[i][0].w;
                hx[4] = (f16_t)br[i][1].x; hx[5] = (f16_t)br[i][1].y;
                hx[6] = (f16_t)br[i][1].z; hx[7] = (f16_t)br[i][1].w;
                *reinterpret_cast<f16x8*>(nb + boff[i]) = hx;
            }
        }
        asm volatile("s_waitcnt lgkmcnt(0)" ::: "memory");
        __builtin_amdgcn_s_barrier();
        __builtin_amdgcn_sched_barrier(0);
    }

    const int r0 = by * 128 + wm * 64 + s4 * 4;
    const int c0 = bx * 192 + wn * 48 + fr;
    #pragma unroll
    for (int ri = 0; ri < 4; ++ri)
        #pragma unroll
        for (int j = 0; j < 3; ++j) {
            const int col = c0 + j * 16;
            #pragma unroll
            for (int rr = 0; rr < 4; ++rr) {
                const int row = r0 + ri * 16 + rr;
                const f16_t v = (f16_t)acc[ri][j][rr];
                uint16_t bits;
                __builtin_memcpy(&bits, &v, 2);
                if (col < 4096)      xq16[(size_t)row * 4096 + col] = bits;
                else if (col < 5120) xk16[(size_t)row * 1024 + (col - 4096)] = bits;
                else                 xv16[(size_t)row * 1024 + (col - 5120)] = bits;
            }
        }
}

// ---------------- Output GEMM: 256x128, fp16, BK=64, 2-buf, grid 256; 2-D XCD partition.
// A (aoh) via global_load_lds; B (wo) reg-staged from native fp32 + cvt.
__global__ __launch_bounds__(512) void gemm_out10(const uint16_t* __restrict__ aoh,
                                                  const float* __restrict__ wo,
                                                  float* __restrict__ out)
{
    __shared__ char lds[2][49152];   // A 32K | B 16K ([kk2][128r][32c])

    const int bid = blockIdx.x;
    const int xcd = bid & 7;
    const int i_  = bid >> 3;
    const int by = (xcd & 1) * 4 + (i_ & 3);
    const int bx = (xcd >> 1) * 8 + (i_ >> 2);
    const int tid = threadIdx.x;
    const int w = tid >> 6, lane = tid & 63;
    const int wm = w >> 2, wn = w & 3;
    const int fr = lane & 15, s4 = lane >> 4;

    // A staging: 32 chunks; wave w stages c = w + 8i, i=0..3
    const uint16_t* spA[4];
    int dofA[4];
    #pragma unroll
    for (int i = 0; i < 4; ++i) {
        const int c = w + 8 * i;
        spA[i] = aoh + (size_t)(2 * by + (c >> 4)) * 524288 + (c & 15) * 512 + lane * 8;
        dofA[i] = c * 1024;
    }

    // B reg-staging: 2 units of 8 fp32 per thread
    const float* bsrc[2];
    int boff[2];
    #pragma unroll
    for (int i = 0; i < 2; ++i) {
        const int v = tid + 512 * i;
        const int row = v >> 3;            // 0..127
        const int s8  = v & 7;
        bsrc[i] = wo + (size_t)(bx * 128 + row) * 4096 + s8 * 8;
        boff[i] = 32768 + (s8 >> 2) * 8192 + row * 64 + (((s8 & 3) ^ ((row >> 1) & 3)) << 4);
    }

    f32x4 acc[8][2] = {};
    float4 br[2][2];

    #pragma unroll
    for (int i = 0; i < 4; ++i)
        __builtin_amdgcn_global_load_lds(
            (const __attribute__((address_space(1))) void*)(spA[i]),
            (__attribute__((address_space(3))) void*)(&lds[0][0] + dofA[i]), 16, 0, 0);
    #pragma unroll
    for (int i = 0; i < 2; ++i) {
        br[i][0] = *reinterpret_cast<const float4*>(bsrc[i]);
        br[i][1] = *reinterpret_cast<const float4*>(bsrc[i] + 4);
    }
    asm volatile("s_waitcnt vmcnt(0)" ::: "memory");
    #pragma unroll
    for (int i = 0; i < 2; ++i) {
        f16x8 hx;
        hx[0] = (f16_t)br[i][0].x; hx[1] = (f16_t)br[i][0].y;
        hx[2] = (f16_t)br[i][0].z; hx[3] = (f16_t)br[i][0].w;
        hx[4] = (f16_t)br[i][1].x; hx[5] = (f16_t)br[i][1].y;
        hx[6] = (f16_t)br[i][1].z; hx[7] = (f16_t)br[i][1].w;
        *reinterpret_cast<f16x8*>(&lds[0][0] + boff[i]) = hx;
    }
    asm volatile("s_waitcnt lgkmcnt(0)" ::: "memory");
    __builtin_amdgcn_s_barrier();
    __builtin_amdgcn_sched_barrier(0);

    for (int t = 0; t < 64; ++t) {
        const char* b = &lds[t & 1][0];
        char* nb = &lds[(t + 1) & 1][0];
        const bool pre = (t + 1 < 64);
        if (pre) {
            #pragma unroll
            for (int i = 0; i < 2; ++i) {
                br[i][0] = *reinterpret_cast<const float4*>(bsrc[i] + (size_t)(t + 1) * 64);
                br[i][1] = *reinterpret_cast<const float4*>(bsrc[i] + (size_t)(t + 1) * 64 + 4);
            }
            #pragma unroll
            for (int i = 0; i < 4; ++i)
                __builtin_amdgcn_global_load_lds(
                    (const __attribute__((address_space(1))) void*)(spA[i] + (size_t)(t + 1) * 8192),
                    (__attribute__((address_space(3))) void*)(nb + dofA[i]), 16, 0, 0);
        }
        #pragma unroll
        for (int kk = 0; kk < 2; ++kk) {
            f16x8 fb[2];
            #pragma unroll
            for (int j = 0; j < 2; ++j) {
                const int cbp = wn * 32 + j * 16 + fr;
                fb[j] = *reinterpret_cast<const f16x8*>(
                    b + 32768 + kk * 8192 + cbp * 64 + ((s4 ^ ((cbp >> 1) & 3)) << 4));
            }
            #pragma unroll
            for (int p = 0; p < 4; ++p) {
                f16x8 fh[2];
                #pragma unroll
                for (int f = 0; f < 2; ++f) {
                    const int rloc = p * 32 + f * 16 + fr;
                    fh[f] = *reinterpret_cast<const f16x8*>(
                        b + wm * 16384 + kk * 8192 + rloc * 64 + ((s4 ^ ((rloc >> 1) & 3)) << 4));
                }
                __builtin_amdgcn_s_setprio(1);
                #pragma unroll
                for (int f = 0; f < 2; ++f)
                    #pragma unroll
                    for (int j = 0; j < 2; ++j)
                        acc[p * 2 + f][j] = __builtin_amdgcn_mfma_f32_16x16x32_f16(fh[f], fb[j], acc[p * 2 + f][j], 0, 0, 0);
                __builtin_amdgcn_s_setprio(0);
            }
        }
        asm volatile("s_waitcnt vmcnt(0)" ::: "memory");
        if (pre) {
            #pragma unroll
            for (int i = 0; i < 2; ++i) {
                f16x8 hx;
                hx[0] = (f16_t)br[i][0].x; hx[1] = (f16_t)br[i][0].y;
                hx[2] = (f16_t)br[i][0].z; hx[3] = (f16_t)br[i][0].w;
                hx[4] = (f16_t)br[i][1].x; hx[5] = (f16_t)br[i][1].y;
                hx[6] = (f16_t)br[i][1].z; hx[7] = (f16_t)br[i][1].w;
                *reinterpret_cast<f16x8*>(nb + boff[i]) = hx;
            }
        }
        asm volatile("s_waitcnt lgkmcnt(0)" ::: "memory");
        __builtin_amdgcn_s_barrier();
        __builtin_amdgcn_sched_barrier(0);
    }

    const int r0 = by * 256 + wm * 128 + s4 * 4;
    const int c0 = bx * 128 + wn * 32 + fr;
    #pragma unroll
    for (int ri = 0; ri < 8; ++ri)
        #pragma unroll
        for (int j = 0; j < 2; ++j)
            #pragma unroll
            for (int rr = 0; rr < 4; ++rr)
                out[(size_t)(r0 + ri * 16 + rr) * 4096 + c0 + j * 16] = acc[ri][j][rr];
}

// ---------------- conv_kv: fp16 K/V in; rope on K; fp16 swizzled tiles out ----------------
__global__ __launch_bounds__(256) void conv_kv(const uint16_t* __restrict__ xk16,
                                               const uint16_t* __restrict__ xv16,
                                               uint16_t* __restrict__ kvg)
{
    __shared__ float V[32][129];
    const int t = blockIdx.x;
    const int h = blockIdx.y;
    const int tid = threadIdx.x;
    uint16_t* tile = kvg + ((size_t)(h * 64 + t)) * 8192;

    #pragma unroll
    for (int i = 0; i < 4; ++i) {
        const int v = i * 256 + tid;
        const int row = v >> 5, c4 = (v & 31) * 4;
        f16x4 hv = *reinterpret_cast<const f16x4*>(&xv16[(size_t)(t * 32 + row) * 1024 + h * 128 + c4]);
        #pragma unroll
        for (int e = 0; e < 4; ++e) V[row][c4 + e] = (float)hv[e];
    }

    {
        const int r = tid >> 3;
        const int d0 = (tid & 7) * 16;
        const int pos_ = t * 32 + r;
        float f[16];
        const uint16_t* kr = &xk16[(size_t)pos_ * 1024 + h * 128 + d0];
        f16x8 k0 = *reinterpret_cast<const f16x8*>(kr);
        f16x8 k1 = *reinterpret_cast<const f16x8*>(kr + 8);
        #pragma unroll
        for (int e = 0; e < 8; ++e) { f[e] = (float)k0[e]; f[8 + e] = (float)k1[e]; }
        #pragma unroll
        for (int i = 0; i < 8; ++i) {
            const int j = (d0 >> 1) + i;
            const float invf = exp2f(-(float)j * ROPE_C);
            const float ang = (float)pos_ * invf;
            float sn, cs;
            __sincosf(ang, &sn, &cs);
            const float x1 = f[2 * i], x2 = f[2 * i + 1];
            f[2 * i]     = x1 * cs - x2 * sn;
            f[2 * i + 1] = x1 * sn + x2 * cs;
        }
        #pragma unroll
        for (int cc = 0; cc < 2; ++cc) {
            f16x8 hv;
            #pragma unroll
            for (int e = 0; e < 8; ++e) hv[e] = (f16_t)f[cc * 8 + e];
            const int c = (d0 >> 3) + cc;
            const int pos = r * 128 + ((c ^ (r & 15)) << 3);
            *reinterpret_cast<f16x8*>(&tile[pos]) = hv;
        }
    }
    __syncthreads();
    {
        const int d = tid >> 1;
        const int k0 = (tid & 1) * 16;
        float g[16];
        #pragma unroll
        for (int j = 0; j < 16; ++j) g[j] = V[k0 + j][d];
        #pragma unroll
        for (int cc = 0; cc < 2; ++cc) {
            f16x8 hv;
            #pragma unroll
            for (int e = 0; e < 8; ++e) hv[e] = (f16_t)g[cc * 8 + e];
            const int c = (k0 >> 3) + cc;
            const int pos = 4096 + d * 32 + ((c ^ ((d >> 1) & 3)) << 3);
            *reinterpret_cast<f16x8*>(&tile[pos]) = hv;
        }
    }
}

// ---------------- MFMA flash attention (round-16 proven: 512 thr, QBLK 256, grid 256) ----------------
__device__ __forceinline__ uint cvtpkh(float lo, float hi) {
    uint r;
    asm("v_cvt_pkrtz_f16_f32 %0, %1, %2" : "=v"(r) : "v"(lo), "v"(hi));
    return r;
}
__device__ __forceinline__ void permswap(uint& a, uint& b) {
    asm("v_permlane32_swap_b32 %0, %1" : "+v"(a), "+v"(b));
}
__device__ __forceinline__ f16x8 pack4h(uint w0, uint w1, uint w2, uint w3) {
    union { uint u[4]; f16x8 v; } t;
    t.u[0] = w0; t.u[1] = w1; t.u[2] = w2; t.u[3] = w3;
    return t.v;
}

__global__ __launch_bounds__(512, 2) void attn_mfma(const uint16_t* __restrict__ xq16,
                                                    const uint16_t* __restrict__ kvg,
                                                    uint16_t* __restrict__ aoh)
{
    __shared__ char lds[2][16384];

    const int b = blockIdx.x;
    const int kvh = b & 7;
    const int r = b >> 3;
    const int h = kvh * 4 + (r & 3);
    const int q0 = (r >> 2) * 256;
    const int tid = threadIdx.x;
    const int w = tid >> 6;
    const int lane = tid & 63;
    const int ln31 = lane & 31;
    const int hi = lane >> 5;

    const int q = q0 + w * 32 + ln31;
    const uint16_t* qrow = xq16 + (size_t)q * 4096 + h * 128;
    f16x8 Qh[8];
    #pragma unroll
    for (int ks = 0; ks < 8; ++ks) {
        const int dbase = ks * 16 + hi * 8;
        f16x8 raw = *reinterpret_cast<const f16x8*>(qrow + dbase);
        float f[8];
        #pragma unroll
        for (int e = 0; e < 8; ++e) f[e] = (float)raw[e];
        #pragma unroll
        for (int i = 0; i < 4; ++i) {
            const int j = (dbase >> 1) + i;
            const float invf = exp2f(-(float)j * ROPE_C);
            const float ang = (float)q * invf;
            float sn, cs;
            __sincosf(ang, &sn, &cs);
            const float x1 = f[2 * i], x2 = f[2 * i + 1];
            f[2 * i]     = (x1 * cs - x2 * sn) * 0.08838834764831845f;
            f[2 * i + 1] = (x1 * sn + x2 * cs) * 0.08838834764831845f;
        }
        #pragma unroll
        for (int e = 0; e < 8; ++e) Qh[ks][e] = (f16_t)f[e];
    }

    const char* gkv = (const char*)kvg + (size_t)kvh * 64 * 16384;

    f32x16 oacc[4] = {{}, {}, {}, {}};
    float m = -3.0e38f, l = 0.f;

    {
        #pragma unroll
        for (int i = 0; i < 2; ++i) {
            const int chunk = i * 8 + w;
            __builtin_amdgcn_global_load_lds(
                (const __attribute__((address_space(1))) void*)(gkv + chunk * 1024 + lane * 16),
                (__attribute__((address_space(3))) void*)(&lds[0][chunk * 1024]),
                16, 0, 0);
        }
    }

    for (int t = 0; t < 64; ++t) {
        __syncthreads();
        if (t + 1 < 64) {
            const char* g = gkv + (size_t)(t + 1) * 16384;
            const int buf = (t + 1) & 1;
            #pragma unroll
            for (int i = 0; i < 2; ++i) {
                const int chunk = i * 8 + w;
                __builtin_amdgcn_global_load_lds(
                    (const __attribute__((address_space(1))) void*)(g + chunk * 1024 + lane * 16),
                    (__attribute__((address_space(3))) void*)(&lds[buf][chunk * 1024]),
                    16, 0, 0);
            }
        }
        const int cur = t & 1;
        const char* Kf = lds[cur];
        const char* Vf = lds[cur] + 8192;

        f32x16 s0 = {}, s1 = {};
        __builtin_amdgcn_s_setprio(1);
        #pragma unroll
        for (int ks = 0; ks < 8; ++ks) {
            const int byt = ln31 * 256 + ((ks * 32 + hi * 16) ^ ((ln31 & 15) << 4));
            f16x8 a = *reinterpret_cast<const f16x8*>(Kf + byt);
            if (ks & 1) s1 = __builtin_amdgcn_mfma_f32_32x32x16_f16(a, Qh[ks], s1, 0, 0, 0);
            else        s0 = __builtin_amdgcn_mfma_f32_32x32x16_f16(a, Qh[ks], s0, 0, 0, 0);
        }
        __builtin_amdgcn_s_setprio(0);
        f32x16 s = s0 + s1;

        float pmax = s[0];
        #pragma unroll
        for (int jj = 1; jj < 16; ++jj) pmax = fmaxf(pmax, s[jj]);
        pmax = fmaxf(pmax, __shfl_xor(pmax, 32));
        if (!__all(pmax - m <= 8.0f)) {
            const float mnew = fmaxf(m, pmax);
            const float corr = __expf(m - mnew);
            l *= corr;
            #pragma unroll
            for (int dt = 0; dt < 4; ++dt) oacc[dt] *= corr;
            m = mnew;
        }
        float psum = 0.f;
        #pragma unroll
        for (int jj = 0; jj < 16; ++jj) {
            float pv = __expf(s[jj] - m);
            s[jj] = pv;
            psum += pv;
        }
        psum += __shfl_xor(psum, 32);
        l += psum;

        #pragma unroll
        for (int ks = 0; ks < 2; ++ks) {
            const int b0 = ks * 8;
            uint wa = cvtpkh(s[b0 + 0], s[b0 + 1]);
            uint wb = cvtpkh(s[b0 + 2], s[b0 + 3]);
            uint wc = cvtpkh(s[b0 + 4], s[b0 + 5]);
            uint wd = cvtpkh(s[b0 + 6], s[b0 + 7]);
            permswap(wa, wc); permswap(wb, wd);
            f16x8 Pf = pack4h(wa, wb, wc, wd);
            __builtin_amdgcn_s_setprio(1);
            #pragma unroll
            for (int dt = 0; dt < 4; ++dt) {
                const int row = dt * 32 + ln31;
                const int byt = row * 64 + ((ks * 32 + hi * 16) ^ (((row >> 1) & 3) << 4));
                f16x8 vh = *reinterpret_cast<const f16x8*>(Vf + byt);
                oacc[dt] = __builtin_amdgcn_mfma_f32_32x32x16_f16(vh, Pf, oacc[dt], 0, 0, 0);
            }
            __builtin_amdgcn_s_setprio(0);
        }
    }

    const float invl = 1.0f / l;
    const int p   = q >> 7;
    const int rr_ = q & 127;
    const int rsw = (rr_ >> 1) & 3;
    #pragma unroll
    for (int dt = 0; dt < 4; ++dt) {
        const int kb = h * 4 + dt;
        uint16_t* bh = aoh + ((size_t)p * 128 + kb) * 4096;
        #pragma unroll
        for (int g4 = 0; g4 < 4; ++g4) {
            f16x4 hv;
            #pragma unroll
            for (int e = 0; e < 4; ++e)
                hv[e] = (f16_t)(oacc[dt][g4 * 4 + e] * invl);
            const int pos = rr_ * 32 + ((g4 ^ rsw) << 3) + 4 * hi;
            *reinterpret_cast<f16x4*>(&bh[pos]) = hv;
        }
    }
}

extern "C" void kernel_launch(void* const* d_in, const int* in_sizes, int n_in,
                              void* d_out, int out_size, void* d_ws, size_t ws_size,
                              hipStream_t stream)
{
    const float* x  = (const float*)d_in[0];
    const float* wq = (const float*)d_in[1];
    const float* wk = (const float*)d_in[2];
    const float* wv = (const float*)d_in[3];
    const float* wo = (const float*)d_in[4];
    float* out = (float*)d_out;

    float* ws = (float*)d_ws;
    uint16_t* xq16 = (uint16_t*)ws;                // fp16 Q [2048][4096]
    uint16_t* kvg  = (uint16_t*)(ws + 8388608);    // fp16 K/V tiles (8.4 MB)
    uint16_t* xk16 = (uint16_t*)(ws + 12582912);
    uint16_t* xv16 = (uint16_t*)(ws + 14680064);
    uint16_t* aoh  = (uint16_t*)(ws + 12582912);   // reuses xk slot after conv_kv
    uint16_t* xh   = (uint16_t*)(ws + 20971520);   // fp16 packed x

    dim3 blk(256);
    repack_x16<<<dim3(128, 16), blk, 0, stream>>>(x, xh);
    gemm_qkv10<<<dim3(512), dim3(512), 0, stream>>>(xh, wq, wk, wv, xq16, xk16, xv16);
    conv_kv   <<<dim3(64, 8), blk, 0, stream>>>(xk16, xv16, kvg);
    attn_mfma <<<dim3(256), dim3(512), 0, stream>>>(xq16, kvg, aoh);
    gemm_out10<<<dim3(256), dim3(512), 0, stream>>>(aoh, wo, out);
}

// Round 19
// 340.392 us; speedup vs baseline: 1.1629x; 1.1629x over previous
//
#include <hip/hip_runtime.h>
#include <hip/hip_bf16.h>

typedef _Float16 f16_t;
typedef unsigned int uint;
typedef __attribute__((ext_vector_type(8))) _Float16 f16x8;
typedef __attribute__((ext_vector_type(4))) _Float16 f16x4;
typedef __attribute__((ext_vector_type(4))) float f32x4;
typedef __attribute__((ext_vector_type(16))) float f32x16;

#define ROPE_C (13.287712379549449f / 64.0f)   // log2(10000)/64; invf(j)=exp2(-j*ROPE_C)

// ---------------- merged repack: x (blocks 0..2047), wq|wk|wv 96-pan (2048..10239), wo (10240..14335) ----------------
__global__ __launch_bounds__(256) void repack_all(const float* __restrict__ x,
                                                  const float* __restrict__ wq,
                                                  const float* __restrict__ wk,
                                                  const float* __restrict__ wv,
                                                  const float* __restrict__ wo,
                                                  uint16_t* __restrict__ xh,
                                                  uint16_t* __restrict__ wqkv,
                                                  uint16_t* __restrict__ woh)
{
    const int bid = blockIdx.x;
    const int tid = threadIdx.x;
    const int k4 = tid & 7;
    const int slot = k4 >> 1;
    const int so   = (k4 & 1) * 4;

    if (bid < 2048) {
        // x: [16 pan][128 kb][128 r][32 c]
        const int p  = bid >> 7;
        const int kb = bid & 127;
        const int rr = tid >> 3;
        uint16_t* bh = xh + ((size_t)p * 128 + kb) * 4096;
        #pragma unroll
        for (int it = 0; it < 4; ++it) {
            const int r = it * 32 + rr;
            const float4 v = *reinterpret_cast<const float4*>(
                &x[((size_t)p * 128 + r) * 4096 + kb * 32 + k4 * 4]);
            float f[4] = {v.x, v.y, v.z, v.w};
            f16x4 h;
            #pragma unroll
            for (int e = 0; e < 4; ++e) h[e] = (f16_t)f[e];
            const int pos = r * 32 + ((slot ^ ((r >> 1) & 3)) << 3) + so;
            *reinterpret_cast<f16x4*>(&bh[pos]) = h;
        }
    } else if (bid < 10240) {
        // wq|wk|wv -> [64 pan][128 kb][96 r][32 c]
        const int idx = bid - 2048;
        const int pan = idx >> 7;
        const int kb  = idx & 127;
        uint16_t* bh = wqkv + ((size_t)pan * 128 + kb) * 3072;
        #pragma unroll
        for (int it = 0; it < 3; ++it) {
            const int r = it * 32 + (tid >> 3);
            const int n = pan * 96 + r;
            const float* srow = (n < 4096) ? (wq + (size_t)n * 4096)
                              : (n < 5120) ? (wk + (size_t)(n - 4096) * 4096)
                                           : (wv + (size_t)(n - 5120) * 4096);
            const float4 v = *reinterpret_cast<const float4*>(srow + kb * 32 + k4 * 4);
            float f[4] = {v.x, v.y, v.z, v.w};
            f16x4 h;
            #pragma unroll
            for (int e = 0; e < 4; ++e) h[e] = (f16_t)f[e];
            const int pos = r * 32 + ((slot ^ ((r >> 1) & 3)) << 3) + so;
            *reinterpret_cast<f16x4*>(&bh[pos]) = h;
        }
    } else {
        // wo -> [32 pan][128 kb][128 r][32 c]
        const int idx = bid - 10240;
        const int p  = idx >> 7;
        const int kb = idx & 127;
        const int rr = tid >> 3;
        uint16_t* bh = woh + ((size_t)p * 128 + kb) * 4096;
        #pragma unroll
        for (int it = 0; it < 4; ++it) {
            const int r = it * 32 + rr;
            const float4 v = *reinterpret_cast<const float4*>(
                &wo[((size_t)p * 128 + r) * 4096 + kb * 32 + k4 * 4]);
            float f[4] = {v.x, v.y, v.z, v.w};
            f16x4 h;
            #pragma unroll
            for (int e = 0; e < 4; ++e) h[e] = (f16_t)f[e];
            const int pos = r * 32 + ((slot ^ ((r >> 1) & 3)) << 3) + so;
            *reinterpret_cast<f16x4*>(&bh[pos]) = h;
        }
    }
}

// ---------------- QKV GEMM: 128x192, fp16, BK=64, 2-buf, grid 512; 2-D XCD partition ----------------
__global__ __launch_bounds__(512) void gemm_qkv9(const uint16_t* __restrict__ xh,
                                                 const uint16_t* __restrict__ wqkv,
                                                 uint16_t* __restrict__ xq16,
                                                 uint16_t* __restrict__ xk16,
                                                 uint16_t* __restrict__ xv16)
{
    __shared__ char lds[2][40960];

    const int bid = blockIdx.x;
    const int xcd = bid & 7;
    const int i_  = bid >> 3;
    const int by = (xcd & 1) * 8 + (i_ & 7);
    const int bx = (xcd >> 1) * 8 + (i_ >> 3);
    const int tid = threadIdx.x;
    const int w = tid >> 6, lane = tid & 63;
    const int wm = w >> 2, wn = w & 3;
    const int fr = lane & 15, s4 = lane >> 4;

    const uint16_t* sp[5];
    int dof[5];
    int stridec[5];
    #pragma unroll
    for (int i = 0; i < 5; ++i) {
        const int c = w + 8 * i;
        if (c < 16) {
            const int kk = c >> 3, inner = c & 7;
            sp[i] = xh + (size_t)by * 524288 + kk * 4096 + inner * 512 + lane * 8;
            dof[i] = c * 1024;
            stridec[i] = 8192;
        } else {
            const int cb = c - 16;
            const int pan = cb / 12, rem = cb % 12;
            const int kk = rem / 6, inner = rem % 6;
            sp[i] = wqkv + (size_t)(bx * 2 + pan) * 393216 + kk * 3072 + inner * 512 + lane * 8;
            dof[i] = 16384 + cb * 1024;
            stridec[i] = 6144;
        }
    }

    f32x4 acc[4][3] = {};

    #pragma unroll
    for (int i = 0; i < 5; ++i)
        __builtin_amdgcn_global_load_lds(
            (const __attribute__((address_space(1))) void*)(sp[i]),
            (__attribute__((address_space(3))) void*)(&lds[0][0] + dof[i]), 16, 0, 0);
    asm volatile("s_waitcnt vmcnt(0)" ::: "memory");
    __builtin_amdgcn_s_barrier();
    __builtin_amdgcn_sched_barrier(0);

    for (int t = 0; t < 64; ++t) {
        const char* b = &lds[t & 1][0];
        if (t + 1 < 64) {
            char* nb = &lds[(t + 1) & 1][0];
            #pragma unroll
            for (int i = 0; i < 5; ++i)
                __builtin_amdgcn_global_load_lds(
                    (const __attribute__((address_space(1))) void*)(sp[i] + (size_t)(t + 1) * stridec[i]),
                    (__attribute__((address_space(3))) void*)(nb + dof[i]), 16, 0, 0);
        }
        #pragma unroll
        for (int kk = 0; kk < 2; ++kk) {
            f16x8 fb[3];
            #pragma unroll
            for (int j = 0; j < 3; ++j) {
                const int cbp = wn * 48 + j * 16 + fr;
                const int pan = (cbp >= 96) ? 1 : 0;
                const int rb = cbp - pan * 96;
                fb[j] = *reinterpret_cast<const f16x8*>(
                    b + 16384 + pan * 12288 + kk * 6144 + rb * 64 + ((s4 ^ ((rb >> 1) & 3)) << 4));
            }
            #pragma unroll
            for (int ri = 0; ri < 4; ++ri) {
                const int rloc = wm * 64 + ri * 16 + fr;
                f16x8 fh = *reinterpret_cast<const f16x8*>(
                    b + kk * 8192 + rloc * 64 + ((s4 ^ ((rloc >> 1) & 3)) << 4));
                __builtin_amdgcn_s_setprio(1);
                #pragma unroll
                for (int j = 0; j < 3; ++j)
                    acc[ri][j] = __builtin_amdgcn_mfma_f32_16x16x32_f16(fh, fb[j], acc[ri][j], 0, 0, 0);
                __builtin_amdgcn_s_setprio(0);
            }
        }
        asm volatile("s_waitcnt vmcnt(0)" ::: "memory");
        __builtin_amdgcn_s_barrier();
        __builtin_amdgcn_sched_barrier(0);
    }

    const int r0 = by * 128 + wm * 64 + s4 * 4;
    const int c0 = bx * 192 + wn * 48 + fr;
    #pragma unroll
    for (int ri = 0; ri < 4; ++ri)
        #pragma unroll
        for (int j = 0; j < 3; ++j) {
            const int col = c0 + j * 16;
            #pragma unroll
            for (int rr = 0; rr < 4; ++rr) {
                const int row = r0 + ri * 16 + rr;
                const f16_t v = (f16_t)acc[ri][j][rr];
                uint16_t bits;
                __builtin_memcpy(&bits, &v, 2);
                if (col < 4096)      xq16[(size_t)row * 4096 + col] = bits;
                else if (col < 5120) xk16[(size_t)row * 1024 + (col - 4096)] = bits;
                else                 xv16[(size_t)row * 1024 + (col - 5120)] = bits;
            }
        }
}

// ---------------- Output GEMM: 256x128, fp16, BK=64, 2-buf, grid 256; 2-D XCD partition ----------------
__global__ __launch_bounds__(512) void gemm_out8(const uint16_t* __restrict__ aoh,
                                                 const uint16_t* __restrict__ woh,
                                                 float* __restrict__ out)
{
    __shared__ char lds[2][49152];

    const int bid = blockIdx.x;
    const int xcd = bid & 7;
    const int i_  = bid >> 3;
    const int by = (xcd & 1) * 4 + (i_ & 3);
    const int bx = (xcd >> 1) * 8 + (i_ >> 2);
    const int tid = threadIdx.x;
    const int w = tid >> 6, lane = tid & 63;
    const int wm = w >> 2, wn = w & 3;
    const int fr = lane & 15, s4 = lane >> 4;

    const uint16_t* sp[6];
    int dof[6];
    #pragma unroll
    for (int i = 0; i < 6; ++i) {
        const int c = w + 8 * i;
        if (c < 32) {
            const int pan = c >> 4, sub = c & 15;
            sp[i] = aoh + (size_t)(2 * by + pan) * 524288 + sub * 512 + lane * 8;
            dof[i] = c * 1024;
        } else {
            sp[i] = woh + (size_t)bx * 524288 + (c - 32) * 512 + lane * 8;
            dof[i] = 32768 + (c - 32) * 1024;
        }
    }

    f32x4 acc[8][2] = {};

    #pragma unroll
    for (int i = 0; i < 6; ++i)
        __builtin_amdgcn_global_load_lds(
            (const __attribute__((address_space(1))) void*)(sp[i]),
            (__attribute__((address_space(3))) void*)(&lds[0][0] + dof[i]), 16, 0, 0);
    asm volatile("s_waitcnt vmcnt(0)" ::: "memory");
    __builtin_amdgcn_s_barrier();
    __builtin_amdgcn_sched_barrier(0);

    for (int t = 0; t < 64; ++t) {
        const char* b = &lds[t & 1][0];
        if (t + 1 < 64) {
            char* nb = &lds[(t + 1) & 1][0];
            #pragma unroll
            for (int i = 0; i < 6; ++i)
                __builtin_amdgcn_global_load_lds(
                    (const __attribute__((address_space(1))) void*)(sp[i] + (size_t)(t + 1) * 8192),
                    (__attribute__((address_space(3))) void*)(nb + dof[i]), 16, 0, 0);
        }
        #pragma unroll
        for (int kk = 0; kk < 2; ++kk) {
            f16x8 fb[2];
            #pragma unroll
            for (int j = 0; j < 2; ++j) {
                const int cbp = wn * 32 + j * 16 + fr;
                fb[j] = *reinterpret_cast<const f16x8*>(
                    b + 32768 + kk * 8192 + cbp * 64 + ((s4 ^ ((cbp >> 1) & 3)) << 4));
            }
            #pragma unroll
            for (int p = 0; p < 4; ++p) {
                f16x8 fh[2];
                #pragma unroll
                for (int f = 0; f < 2; ++f) {
                    const int rloc = p * 32 + f * 16 + fr;
                    fh[f] = *reinterpret_cast<const f16x8*>(
                        b + wm * 16384 + kk * 8192 + rloc * 64 + ((s4 ^ ((rloc >> 1) & 3)) << 4));
                }
                __builtin_amdgcn_s_setprio(1);
                #pragma unroll
                for (int f = 0; f < 2; ++f)
                    #pragma unroll
                    for (int j = 0; j < 2; ++j)
                        acc[p * 2 + f][j] = __builtin_amdgcn_mfma_f32_16x16x32_f16(fh[f], fb[j], acc[p * 2 + f][j], 0, 0, 0);
                __builtin_amdgcn_s_setprio(0);
            }
        }
        asm volatile("s_waitcnt vmcnt(0)" ::: "memory");
        __builtin_amdgcn_s_barrier();
        __builtin_amdgcn_sched_barrier(0);
    }

    const int r0 = by * 256 + wm * 128 + s4 * 4;
    const int c0 = bx * 128 + wn * 32 + fr;
    #pragma unroll
    for (int ri = 0; ri < 8; ++ri)
        #pragma unroll
        for (int j = 0; j < 2; ++j)
            #pragma unroll
            for (int rr = 0; rr < 4; ++rr)
                out[(size_t)(r0 + ri * 16 + rr) * 4096 + c0 + j * 16] = acc[ri][j][rr];
}

// ---------------- conv_kv: fp16 K/V in; rope on K; fp16 swizzled tiles out ----------------
// Tile = 8192 uint16 (16 KB): K [32 kv][128 d] at 0, Vt [128 d][32 kv] at 4096.
// V slot swizzle: slot ^= (d>>1)&3  (balanced across bank quads for PV reads).
__global__ __launch_bounds__(256) void conv_kv(const uint16_t* __restrict__ xk16,
                                               const uint16_t* __restrict__ xv16,
                                               uint16_t* __restrict__ kvg)
{
    __shared__ float V[32][129];
    const int t = blockIdx.x;
    const int h = blockIdx.y;
    const int tid = threadIdx.x;
    uint16_t* tile = kvg + ((size_t)(h * 64 + t)) * 8192;

    #pragma unroll
    for (int i = 0; i < 4; ++i) {
        const int v = i * 256 + tid;
        const int row = v >> 5, c4 = (v & 31) * 4;
        f16x4 hv = *reinterpret_cast<const f16x4*>(&xv16[(size_t)(t * 32 + row) * 1024 + h * 128 + c4]);
        #pragma unroll
        for (int e = 0; e < 4; ++e) V[row][c4 + e] = (float)hv[e];
    }

    {
        const int r = tid >> 3;
        const int d0 = (tid & 7) * 16;
        const int pos_ = t * 32 + r;
        float f[16];
        const uint16_t* kr = &xk16[(size_t)pos_ * 1024 + h * 128 + d0];
        f16x8 k0 = *reinterpret_cast<const f16x8*>(kr);
        f16x8 k1 = *reinterpret_cast<const f16x8*>(kr + 8);
        #pragma unroll
        for (int e = 0; e < 8; ++e) { f[e] = (float)k0[e]; f[8 + e] = (float)k1[e]; }
        #pragma unroll
        for (int i = 0; i < 8; ++i) {
            const int j = (d0 >> 1) + i;
            const float invf = exp2f(-(float)j * ROPE_C);
            const float ang = (float)pos_ * invf;
            float sn, cs;
            __sincosf(ang, &sn, &cs);
            const float x1 = f[2 * i], x2 = f[2 * i + 1];
            f[2 * i]     = x1 * cs - x2 * sn;
            f[2 * i + 1] = x1 * sn + x2 * cs;
        }
        #pragma unroll
        for (int cc = 0; cc < 2; ++cc) {
            f16x8 hv;
            #pragma unroll
            for (int e = 0; e < 8; ++e) hv[e] = (f16_t)f[cc * 8 + e];
            const int c = (d0 >> 3) + cc;
            const int pos = r * 128 + ((c ^ (r & 15)) << 3);
            *reinterpret_cast<f16x8*>(&tile[pos]) = hv;
        }
    }
    __syncthreads();
    {
        const int d = tid >> 1;
        const int k0 = (tid & 1) * 16;
        float g[16];
        #pragma unroll
        for (int j = 0; j < 16; ++j) g[j] = V[k0 + j][d];
        #pragma unroll
        for (int cc = 0; cc < 2; ++cc) {
            f16x8 hv;
            #pragma unroll
            for (int e = 0; e < 8; ++e) hv[e] = (f16_t)g[cc * 8 + e];
            const int c = (k0 >> 3) + cc;
            const int pos = 4096 + d * 32 + ((c ^ ((d >> 1) & 3)) << 3);
            *reinterpret_cast<f16x8*>(&tile[pos]) = hv;
        }
    }
}

// ---------------- MFMA flash attention (512 thr, QBLK 256, grid 256; proven 347-µs config) ----------------
__device__ __forceinline__ uint cvtpkh(float lo, float hi) {
    uint r;
    asm("v_cvt_pkrtz_f16_f32 %0, %1, %2" : "=v"(r) : "v"(lo), "v"(hi));
    return r;
}
__device__ __forceinline__ void permswap(uint& a, uint& b) {
    asm("v_permlane32_swap_b32 %0, %1" : "+v"(a), "+v"(b));
}
__device__ __forceinline__ f16x8 pack4h(uint w0, uint w1, uint w2, uint w3) {
    union { uint u[4]; f16x8 v; } t;
    t.u[0] = w0; t.u[1] = w1; t.u[2] = w2; t.u[3] = w3;
    return t.v;
}

__global__ __launch_bounds__(512, 2) void attn_mfma(const uint16_t* __restrict__ xq16,
                                                    const uint16_t* __restrict__ kvg,
                                                    uint16_t* __restrict__ aoh)
{
    __shared__ char lds[2][16384];

    const int b = blockIdx.x;
    const int kvh = b & 7;
    const int r = b >> 3;
    const int h = kvh * 4 + (r & 3);
    const int q0 = (r >> 2) * 256;
    const int tid = threadIdx.x;
    const int w = tid >> 6;
    const int lane = tid & 63;
    const int ln31 = lane & 31;
    const int hi = lane >> 5;

    const int q = q0 + w * 32 + ln31;
    const uint16_t* qrow = xq16 + (size_t)q * 4096 + h * 128;
    f16x8 Qh[8];
    #pragma unroll
    for (int ks = 0; ks < 8; ++ks) {
        const int dbase = ks * 16 + hi * 8;
        f16x8 raw = *reinterpret_cast<const f16x8*>(qrow + dbase);
        float f[8];
        #pragma unroll
        for (int e = 0; e < 8; ++e) f[e] = (float)raw[e];
        #pragma unroll
        for (int i = 0; i < 4; ++i) {
            const int j = (dbase >> 1) + i;
            const float invf = exp2f(-(float)j * ROPE_C);
            const float ang = (float)q * invf;
            float sn, cs;
            __sincosf(ang, &sn, &cs);
            const float x1 = f[2 * i], x2 = f[2 * i + 1];
            f[2 * i]     = (x1 * cs - x2 * sn) * 0.08838834764831845f;
            f[2 * i + 1] = (x1 * sn + x2 * cs) * 0.08838834764831845f;
        }
        #pragma unroll
        for (int e = 0; e < 8; ++e) Qh[ks][e] = (f16_t)f[e];
    }

    const char* gkv = (const char*)kvg + (size_t)kvh * 64 * 16384;

    f32x16 oacc[4] = {{}, {}, {}, {}};
    float m = -3.0e38f, l = 0.f;

    {
        #pragma unroll
        for (int i = 0; i < 2; ++i) {
            const int chunk = i * 8 + w;
            __builtin_amdgcn_global_load_lds(
                (const __attribute__((address_space(1))) void*)(gkv + chunk * 1024 + lane * 16),
                (__attribute__((address_space(3))) void*)(&lds[0][chunk * 1024]),
                16, 0, 0);
        }
    }

    for (int t = 0; t < 64; ++t) {
        __syncthreads();
        if (t + 1 < 64) {
            const char* g = gkv + (size_t)(t + 1) * 16384;
            const int buf = (t + 1) & 1;
            #pragma unroll
            for (int i = 0; i < 2; ++i) {
                const int chunk = i * 8 + w;
                __builtin_amdgcn_global_load_lds(
                    (const __attribute__((address_space(1))) void*)(g + chunk * 1024 + lane * 16),
                    (__attribute__((address_space(3))) void*)(&lds[buf][chunk * 1024]),
                    16, 0, 0);
            }
        }
        const int cur = t & 1;
        const char* Kf = lds[cur];
        const char* Vf = lds[cur] + 8192;

        f32x16 s0 = {}, s1 = {};
        __builtin_amdgcn_s_setprio(1);
        #pragma unroll
        for (int ks = 0; ks < 8; ++ks) {
            const int byt = ln31 * 256 + ((ks * 32 + hi * 16) ^ ((ln31 & 15) << 4));
            f16x8 a = *reinterpret_cast<const f16x8*>(Kf + byt);
            if (ks & 1) s1 = __builtin_amdgcn_mfma_f32_32x32x16_f16(a, Qh[ks], s1, 0, 0, 0);
            else        s0 = __builtin_amdgcn_mfma_f32_32x32x16_f16(a, Qh[ks], s0, 0, 0, 0);
        }
        __builtin_amdgcn_s_setprio(0);
        f32x16 s = s0 + s1;

        float pmax = s[0];
        #pragma unroll
        for (int jj = 1; jj < 16; ++jj) pmax = fmaxf(pmax, s[jj]);
        pmax = fmaxf(pmax, __shfl_xor(pmax, 32));
        if (!__all(pmax - m <= 8.0f)) {
            const float mnew = fmaxf(m, pmax);
            const float corr = __expf(m - mnew);
            l *= corr;
            #pragma unroll
            for (int dt = 0; dt < 4; ++dt) oacc[dt] *= corr;
            m = mnew;
        }
        float psum = 0.f;
        #pragma unroll
        for (int jj = 0; jj < 16; ++jj) {
            float pv = __expf(s[jj] - m);
            s[jj] = pv;
            psum += pv;
        }
        psum += __shfl_xor(psum, 32);
        l += psum;

        #pragma unroll
        for (int ks = 0; ks < 2; ++ks) {
            const int b0 = ks * 8;
            uint wa = cvtpkh(s[b0 + 0], s[b0 + 1]);
            uint wb = cvtpkh(s[b0 + 2], s[b0 + 3]);
            uint wc = cvtpkh(s[b0 + 4], s[b0 + 5]);
            uint wd = cvtpkh(s[b0 + 6], s[b0 + 7]);
            permswap(wa, wc); permswap(wb, wd);
            f16x8 Pf = pack4h(wa, wb, wc, wd);
            __builtin_amdgcn_s_setprio(1);
            #pragma unroll
            for (int dt = 0; dt < 4; ++dt) {
                const int row = dt * 32 + ln31;
                const int byt = row * 64 + ((ks * 32 + hi * 16) ^ (((row >> 1) & 3) << 4));
                f16x8 vh = *reinterpret_cast<const f16x8*>(Vf + byt);
                oacc[dt] = __builtin_amdgcn_mfma_f32_32x32x16_f16(vh, Pf, oacc[dt], 0, 0, 0);
            }
            __builtin_amdgcn_s_setprio(0);
        }
    }

    const float invl = 1.0f / l;
    const int p   = q >> 7;
    const int rr_ = q & 127;
    const int rsw = (rr_ >> 1) & 3;
    #pragma unroll
    for (int dt = 0; dt < 4; ++dt) {
        const int kb = h * 4 + dt;
        uint16_t* bh = aoh + ((size_t)p * 128 + kb) * 4096;
        #pragma unroll
        for (int g4 = 0; g4 < 4; ++g4) {
            f16x4 hv;
            #pragma unroll
            for (int e = 0; e < 4; ++e)
                hv[e] = (f16_t)(oacc[dt][g4 * 4 + e] * invl);
            const int pos = rr_ * 32 + ((g4 ^ rsw) << 3) + 4 * hi;
            *reinterpret_cast<f16x4*>(&bh[pos]) = hv;
        }
    }
}

extern "C" void kernel_launch(void* const* d_in, const int* in_sizes, int n_in,
                              void* d_out, int out_size, void* d_ws, size_t ws_size,
                              hipStream_t stream)
{
    const float* x  = (const float*)d_in[0];
    const float* wq = (const float*)d_in[1];
    const float* wk = (const float*)d_in[2];
    const float* wv = (const float*)d_in[3];
    const float* wo = (const float*)d_in[4];
    float* out = (float*)d_out;

    float* ws = (float*)d_ws;
    uint16_t* xq16 = (uint16_t*)ws;                // fp16 Q [2048][4096]
    uint16_t* kvg  = (uint16_t*)(ws + 8388608);    // fp16 K/V tiles (8.4 MB)
    uint16_t* xk16 = (uint16_t*)(ws + 12582912);
    uint16_t* xv16 = (uint16_t*)(ws + 14680064);
    uint16_t* aoh  = (uint16_t*)(ws + 12582912);   // reuses xk slot after conv_kv
    uint16_t* xh   = (uint16_t*)(ws + 20971520);   // fp16 packed x
    uint16_t* wqkv = (uint16_t*)(ws + 29360128);   // fp16 packed wq|wk|wv
    uint16_t* woh  = (uint16_t*)(ws + 41943040);   // fp16 packed wo

    dim3 blk(256);
    repack_all<<<dim3(14336), blk, 0, stream>>>(x, wq, wk, wv, wo, xh, wqkv, woh);
    gemm_qkv9 <<<dim3(512), dim3(512), 0, stream>>>(xh, wqkv, xq16, xk16, xv16);
    conv_kv   <<<dim3(64, 8), blk, 0, stream>>>(xk16, xv16, kvg);
    attn_mfma <<<dim3(256), dim3(512), 0, stream>>>(xq16, kvg, aoh);
    gemm_out8 <<<dim3(256), dim3(512), 0, stream>>>(aoh, woh, out);
}